// Round 15
// baseline (281.612 us; speedup 1.0000x reference)
//
#include <hip/hip_runtime.h>
#include <hip/hip_bf16.h>
#include <math.h>

// Problem constants
#define B_   16
#define IC_  32
#define HW_  128
#define NF_  8
#define OC_  64
#define K_   5
#define GRP_ 8
#define COTOT_ (OC_ * GRP_)   // 512
#define XTH  132              // padded spatial (128 + 2*2)
#define TAPSTRIDE (COTOT_ * IC_)   // elements per tap in wt
#define XROWB (XTH * IC_ * 2)      // 8448 bytes per xs row
#define HW2  (HW_ * HW_)

typedef short  short8  __attribute__((ext_vector_type(8)));
typedef unsigned short ushort8 __attribute__((ext_vector_type(8)));
typedef float  f32x4   __attribute__((ext_vector_type(4)));

static __device__ inline unsigned short f2bf(float f) {
    unsigned u = __builtin_bit_cast(unsigned, f);
    unsigned r = (u + 0x7FFFu + ((u >> 16) & 1u)) >> 16;
    return (unsigned short)r;
}

// async global -> LDS, 16 bytes per lane (dest = uniform base + lane*16)
__device__ __forceinline__ void gload16(void* lds, const void* g) {
    __builtin_amdgcn_global_load_lds(
        (const __attribute__((address_space(1))) unsigned int*)g,
        (__attribute__((address_space(3))) unsigned int*)lds, 16, 0, 0);
}

// ---------------------------------------------------------------------------
// Kernel 1 (merged): xform (blocks 0..1088) + build_w (blocks 1089..2688)
// xform: x NCHW fp32 -> padded NHWC bf16 xt[b][hp][wp][ic]
// build_w: rotated+mixed weights -> bf16, layout wt[tap25][co512][ic32]
// ---------------------------------------------------------------------------
#define XFORM_BLOCKS 1089   // 16*132*132 / 256
__global__ __launch_bounds__(256) void prep_kernel(
    const float* __restrict__ x,
    const float* __restrict__ kern,
    const float* __restrict__ relaxed,
    unsigned short* __restrict__ xt,
    unsigned short* __restrict__ wt) {
    int tid = threadIdx.x;
    if (blockIdx.x < XFORM_BLOCKS) {
        int idx = blockIdx.x * 256 + tid;
        int wp = idx % XTH;
        int t  = idx / XTH;
        int hp = t % XTH;
        int b  = t / XTH;

        unsigned short vals[IC_];
        bool interior = (hp >= 2) && (hp < 2 + HW_) && (wp >= 2) && (wp < 2 + HW_);
        if (interior) {
            const float* xb = x + ((size_t)b * IC_) * HW2 + (hp - 2) * HW_ + (wp - 2);
            #pragma unroll
            for (int ic = 0; ic < IC_; ++ic)
                vals[ic] = f2bf(xb[(size_t)ic * HW2]);
        } else {
            #pragma unroll
            for (int ic = 0; ic < IC_; ++ic) vals[ic] = 0;
        }
        ushort8* dst = (ushort8*)(xt + (size_t)idx * IC_);
        #pragma unroll
        for (int c = 0; c < 4; ++c) {
            ushort8 v;
            #pragma unroll
            for (int j = 0; j < 8; ++j) v[j] = vals[c * 8 + j];
            dst[c] = v;
        }
    } else {
        int idx = (blockIdx.x - XFORM_BLOCKS) * 256 + tid;   // < 409600
        int ic = idx & (IC_ - 1);
        int t  = idx >> 5;
        int co = t & (COTOT_ - 1);
        int e  = t >> 9;            // ky*5+kx
        int a  = co & (GRP_ - 1);
        int o  = co >> 3;
        int i  = e / K_;            // ky
        int j  = e - i * K_;        // kx

        float theta = -6.283185307179586f / (float)GRP_ * (float)a;
        float cth = cosf(theta), sth = sinf(theta);
        float bx = (2.0f * (float)j + 1.0f) / (float)K_ - 1.0f;
        float by = (2.0f * (float)i + 1.0f) / (float)K_ - 1.0f;
        float gx = cth * bx - sth * by;
        float gy = sth * bx + cth * by;
        float ix = ((gx + 1.0f) * (float)K_ - 1.0f) * 0.5f;
        float iy = ((gy + 1.0f) * (float)K_ - 1.0f) * 0.5f;
        float x0 = floorf(ix), y0 = floorf(iy);
        float wx1 = ix - x0, wy1 = iy - y0;
        float wx0 = 1.0f - wx1, wy0 = 1.0f - wy1;

        float xs2[2]  = {x0, x0 + 1.0f};
        float ys2[2]  = {y0, y0 + 1.0f};
        float wxs[2] = {wx0, wx1};
        float wys[2] = {wy0, wy1};

        float tw[4];
        int   tyc[4], txc[4];
        #pragma unroll
        for (int dy = 0; dy < 2; ++dy) {
            #pragma unroll
            for (int dx = 0; dx < 2; ++dx) {
                float xx = xs2[dx], yy = ys2[dy];
                bool valid = (xx >= 0.0f) && (xx < (float)K_) &&
                             (yy >= 0.0f) && (yy < (float)K_);
                int tp = dy * 2 + dx;
                tw[tp]  = wys[dy] * wxs[dx] * (valid ? 1.0f : 0.0f);
                txc[tp] = (int)fminf(fmaxf(xx, 0.0f), (float)(K_ - 1));
                tyc[tp] = (int)fminf(fmaxf(yy, 0.0f), (float)(K_ - 1));
            }
        }

        float acc = 0.0f;
        #pragma unroll
        for (int n = 0; n < NF_; ++n) {
            const float* kb = kern + ((size_t)((n * OC_ + o) * IC_ + ic)) * (K_ * K_);
            float v = 0.0f;
            #pragma unroll
            for (int tp = 0; tp < 4; ++tp)
                v += kb[tyc[tp] * K_ + txc[tp]] * tw[tp];
            acc += relaxed[n * GRP_ + a] * v;
        }
        wt[idx] = f2bf(acc);
    }
}

// ---------------------------------------------------------------------------
// Kernel 2: MFMA implicit-GEMM conv + leaky relu — PACED (T3+T4)
// block = 512 thr (8 waves) = 256 co x 2 h x 128 w; 1 block/CU, 2 waves/SIMD
// wave  = 128 co x 64 w at one h row (8x4 frags 16x16), acc 128 VGPR
// per tap (ONE paced phase):
//   issue af(t+1) x8 global  ->  bf ds_read x4  ->  s_barrier
//   -> s_waitcnt vmcnt(8) lgkmcnt(0)   [counted: af(t+1) stays in flight]
//   -> setprio(1) -> 32 MFMA -> setprio(0) -> s_barrier
// A global->VGPR reg-dbuf (L1-served, LDS pipe stays ~31%);
// B swizzled LDS slab (verified conflict-free).
// ---------------------------------------------------------------------------
#define PREF_AF(dst, tap) {                                                   \
    const unsigned short* wp_ = wl + (size_t)(tap) * TAPSTRIDE;               \
    _Pragma("unroll")                                                         \
    for (int m = 0; m < 8; ++m)                                               \
        dst[m] = *(const short8*)(wp_ + (size_t)m * 16 * IC_);                \
}

#define READ_BF() {                                                           \
    int base_ = prow + (wq * 64 + pkx + l15) * 64 +                           \
                ((l4 ^ (((pkx + l15) & 7) >> 1)) << 4);                       \
    _Pragma("unroll")                                                         \
    for (int n = 0; n < 4; ++n)                                               \
        bf[n] = *(const short8*)(xsb + base_ + n * 1024);                     \
    if (++pkx == 5) { pkx = 0; prow += XROWB; }                               \
}

#define MFMA32(afx) {                                                         \
    __builtin_amdgcn_s_setprio(1);                                            \
    _Pragma("unroll")                                                         \
    for (int m = 0; m < 8; ++m)                                               \
        _Pragma("unroll")                                                     \
        for (int n = 0; n < 4; ++n)                                           \
            acc[m][n] = __builtin_amdgcn_mfma_f32_16x16x32_bf16(              \
                afx[m], bf[n], acc[m][n], 0, 0, 0);                           \
    __builtin_amdgcn_s_setprio(0);                                            \
}

__global__ __launch_bounds__(512, 2) void conv_mfma_kernel(
    const unsigned short* __restrict__ xt,
    const unsigned short* __restrict__ wt,
    float* __restrict__ out) {
    // 6 rows x 132 w x 32 ic bf16 = 50688 B (chunk-swizzled via source)
    __shared__ __align__(16) unsigned short xs[6 * XTH * IC_];

    int tid  = threadIdx.x;
    int lane = tid & 63;
    int wid  = tid >> 6;          // 0..7
    int l15  = lane & 15;
    int l4   = lane >> 4;         // k-chunk (ic8 group)
    int wr   = wid >> 2;          // co half (0/1)
    int hr   = (wid >> 1) & 1;    // h row (0/1)
    int wq   = wid & 1;           // w half (0/1)

    int hp = blockIdx.x;          // 0..63 -> rows 2*hp, 2*hp+1
    int b  = blockIdx.y;
    int cg = blockIdx.z;          // 0..1, slowest
    int cobase = cg * 256 + wr * 128;
    int h0 = hp * 2;

    // ---- stage x slab rows h0..h0+5 (linear dest, swizzled source) ----
    {
        const unsigned short* xb = xt + (((size_t)b * XTH + h0) * XTH) * IC_;
        #pragma unroll
        for (int i = 0; i < 7; ++i) {
            int sl = i * 512 + tid;     // 16B slots, 3168 total
            if (sl < 3168) {
                int row = sl / 528;
                int rem = sl - row * 528;
                int w   = rem >> 2;
                int p   = rem & 3;
                int c   = p ^ ((w >> 1) & 3);
                gload16(&xs[sl * 8], xb + row * (XTH * IC_) + w * 32 + c * 8);
            }
        }
    }

    // per-lane A base: co = cobase + m*16 + l15, ic-chunk l4
    const unsigned short* wl = wt + (size_t)(cobase + l15) * IC_ + l4 * 8;
    const char* xsb = (const char*)xs;

    short8 afA[8], afB[8];
    PREF_AF(afA, 0);              // overlaps x staging

    f32x4 acc[8][4];
    #pragma unroll
    for (int m = 0; m < 8; ++m)
        #pragma unroll
        for (int n = 0; n < 4; ++n) acc[m][n] = (f32x4)(0.0f);

    __syncthreads();              // xs + af0 ready (drains vmcnt)

    int pkx  = 0;
    int prow = hr * XROWB;
    short8 bf[4];

    #pragma unroll 1
    for (int pi = 0; pi < 12; ++pi) {
        int t0 = pi * 2;
        // ---- tap t0: prefetch af(t0+1), compute with afA ----
        PREF_AF(afB, t0 + 1);
        READ_BF();
        __builtin_amdgcn_s_barrier();
        asm volatile("s_waitcnt vmcnt(8) lgkmcnt(0)" ::: "memory");
        MFMA32(afA);
        __builtin_amdgcn_s_barrier();
        // ---- tap t0+1: prefetch af(t0+2), compute with afB ----
        PREF_AF(afA, t0 + 2);
        READ_BF();
        __builtin_amdgcn_s_barrier();
        asm volatile("s_waitcnt vmcnt(8) lgkmcnt(0)" ::: "memory");
        MFMA32(afB);
        __builtin_amdgcn_s_barrier();
    }
    // ---- tail: tap 24 with afA ----
    READ_BF();
    __builtin_amdgcn_s_barrier();
    asm volatile("s_waitcnt vmcnt(0) lgkmcnt(0)" ::: "memory");
    MFMA32(afA);

    // ---- epilogue: leaky relu + store ----
    int h = h0 + hr;
    float* ob = out + ((size_t)b * COTOT_ + cobase) * HW2
                    + (size_t)h * HW_ + wq * 64;
    #pragma unroll
    for (int m = 0; m < 8; ++m) {
        #pragma unroll
        for (int n = 0; n < 4; ++n) {
            #pragma unroll
            for (int r = 0; r < 4; ++r) {
                int co = m * 16 + l4 * 4 + r;
                int w  = n * 16 + l15;
                float v = acc[m][n][r];
                v = fmaxf(v, 0.01f * v);
                ob[(size_t)co * HW2 + w] = v;
            }
        }
    }
}

extern "C" void kernel_launch(void* const* d_in, const int* in_sizes, int n_in,
                              void* d_out, int out_size, void* d_ws, size_t ws_size,
                              hipStream_t stream) {
    const float* x       = (const float*)d_in[0];
    const float* kernel  = (const float*)d_in[1];
    const float* relaxed = (const float*)d_in[2];
    float* out = (float*)d_out;

    unsigned short* xt = (unsigned short*)d_ws;   // 16*132*132*32*2 = 17,842,176 B
    unsigned short* wt = (unsigned short*)((char*)d_ws + (size_t)B_ * XTH * XTH * IC_ * 2);

    const int prep_blocks = XFORM_BLOCKS + (25 * COTOT_ * IC_) / 256;  // 1089+1600
    prep_kernel<<<prep_blocks, 256, 0, stream>>>(x, kernel, relaxed, xt, wt);

    dim3 grid(HW_ / 2, B_, COTOT_ / 256);
    conv_mfma_kernel<<<grid, 512, 0, stream>>>(xt, wt, out);
}

// Round 16
// 248.613 us; speedup vs baseline: 1.1327x; 1.1327x over previous
//
#include <hip/hip_runtime.h>
#include <hip/hip_bf16.h>
#include <math.h>

// Problem constants
#define B_   16
#define IC_  32
#define HW_  128
#define NF_  8
#define OC_  64
#define K_   5
#define GRP_ 8
#define COTOT_ (OC_ * GRP_)   // 512
#define XTH  132              // padded spatial (128 + 2*2)
#define TAPSTRIDE (COTOT_ * IC_)   // elements per tap in wt
#define XROWB (XTH * IC_ * 2)      // 8448 bytes per xs row
#define HW2  (HW_ * HW_)

typedef short  short8  __attribute__((ext_vector_type(8)));
typedef unsigned short ushort8 __attribute__((ext_vector_type(8)));
typedef float  f32x4   __attribute__((ext_vector_type(4)));

static __device__ inline unsigned short f2bf(float f) {
    unsigned u = __builtin_bit_cast(unsigned, f);
    unsigned r = (u + 0x7FFFu + ((u >> 16) & 1u)) >> 16;
    return (unsigned short)r;
}

// async global -> LDS, 16 bytes per lane (dest = uniform base + lane*16)
__device__ __forceinline__ void gload16(void* lds, const void* g) {
    __builtin_amdgcn_global_load_lds(
        (const __attribute__((address_space(1))) unsigned int*)g,
        (__attribute__((address_space(3))) unsigned int*)lds, 16, 0, 0);
}

// ---------------------------------------------------------------------------
// Kernel 1 (merged): xform (blocks 0..1088) + build_w (blocks 1089..2688)
// xform: x NCHW fp32 -> padded NHWC bf16 xt[b][hp][wp][ic]
// build_w: rotated+mixed weights -> bf16, layout wt[tap25][co512][ic32]
// ---------------------------------------------------------------------------
#define XFORM_BLOCKS 1089   // 16*132*132 / 256
__global__ __launch_bounds__(256) void prep_kernel(
    const float* __restrict__ x,
    const float* __restrict__ kern,
    const float* __restrict__ relaxed,
    unsigned short* __restrict__ xt,
    unsigned short* __restrict__ wt) {
    int tid = threadIdx.x;
    if (blockIdx.x < XFORM_BLOCKS) {
        int idx = blockIdx.x * 256 + tid;
        int wp = idx % XTH;
        int t  = idx / XTH;
        int hp = t % XTH;
        int b  = t / XTH;

        unsigned short vals[IC_];
        bool interior = (hp >= 2) && (hp < 2 + HW_) && (wp >= 2) && (wp < 2 + HW_);
        if (interior) {
            const float* xb = x + ((size_t)b * IC_) * HW2 + (hp - 2) * HW_ + (wp - 2);
            #pragma unroll
            for (int ic = 0; ic < IC_; ++ic)
                vals[ic] = f2bf(xb[(size_t)ic * HW2]);
        } else {
            #pragma unroll
            for (int ic = 0; ic < IC_; ++ic) vals[ic] = 0;
        }
        ushort8* dst = (ushort8*)(xt + (size_t)idx * IC_);
        #pragma unroll
        for (int c = 0; c < 4; ++c) {
            ushort8 v;
            #pragma unroll
            for (int j = 0; j < 8; ++j) v[j] = vals[c * 8 + j];
            dst[c] = v;
        }
    } else {
        int idx = (blockIdx.x - XFORM_BLOCKS) * 256 + tid;   // < 409600
        int ic = idx & (IC_ - 1);
        int t  = idx >> 5;
        int co = t & (COTOT_ - 1);
        int e  = t >> 9;            // ky*5+kx
        int a  = co & (GRP_ - 1);
        int o  = co >> 3;
        int i  = e / K_;            // ky
        int j  = e - i * K_;        // kx

        float theta = -6.283185307179586f / (float)GRP_ * (float)a;
        float cth = cosf(theta), sth = sinf(theta);
        float bx = (2.0f * (float)j + 1.0f) / (float)K_ - 1.0f;
        float by = (2.0f * (float)i + 1.0f) / (float)K_ - 1.0f;
        float gx = cth * bx - sth * by;
        float gy = sth * bx + cth * by;
        float ix = ((gx + 1.0f) * (float)K_ - 1.0f) * 0.5f;
        float iy = ((gy + 1.0f) * (float)K_ - 1.0f) * 0.5f;
        float x0 = floorf(ix), y0 = floorf(iy);
        float wx1 = ix - x0, wy1 = iy - y0;
        float wx0 = 1.0f - wx1, wy0 = 1.0f - wy1;

        float xs2[2]  = {x0, x0 + 1.0f};
        float ys2[2]  = {y0, y0 + 1.0f};
        float wxs[2] = {wx0, wx1};
        float wys[2] = {wy0, wy1};

        float tw[4];
        int   tyc[4], txc[4];
        #pragma unroll
        for (int dy = 0; dy < 2; ++dy) {
            #pragma unroll
            for (int dx = 0; dx < 2; ++dx) {
                float xx = xs2[dx], yy = ys2[dy];
                bool valid = (xx >= 0.0f) && (xx < (float)K_) &&
                             (yy >= 0.0f) && (yy < (float)K_);
                int tp = dy * 2 + dx;
                tw[tp]  = wys[dy] * wxs[dx] * (valid ? 1.0f : 0.0f);
                txc[tp] = (int)fminf(fmaxf(xx, 0.0f), (float)(K_ - 1));
                tyc[tp] = (int)fminf(fmaxf(yy, 0.0f), (float)(K_ - 1));
            }
        }

        float acc = 0.0f;
        #pragma unroll
        for (int n = 0; n < NF_; ++n) {
            const float* kb = kern + ((size_t)((n * OC_ + o) * IC_ + ic)) * (K_ * K_);
            float v = 0.0f;
            #pragma unroll
            for (int tp = 0; tp < 4; ++tp)
                v += kb[tyc[tp] * K_ + txc[tp]] * tw[tp];
            acc += relaxed[n * GRP_ + a] * v;
        }
        wt[idx] = f2bf(acc);
    }
}

// ---------------------------------------------------------------------------
// Kernel 2: MFMA implicit-GEMM conv + leaky relu  (R13 structure, no setprio)
// wave  = 64 co x 128 w x 1 h (4x8 frags 16x16), acc 128 + dbufs ~= 240 VGPR
// block = 4 waves = 64 co x 4 h x 128 w; LDS 67.5 KB -> 2 blocks/CU,
//         2 waves/SIMD, PHASE-DRIFTED free-running (no barriers in loop):
//         sibling block's waves cover store drain + stage latency.
// A: global->VGPR reg-dbuf distance 1 (L1-served, shared by 4 waves).
// B: swizzled LDS slab (verified conflict-free), reg-dbuf'd reads.
// s_setprio REMOVED (m190: negative on pre-8-phase structures).
// ---------------------------------------------------------------------------
#define PREF_AF(dst, tap) {                                                   \
    const unsigned short* wp_ = wl + (size_t)(tap) * TAPSTRIDE;               \
    _Pragma("unroll")                                                         \
    for (int m = 0; m < 4; ++m)                                               \
        dst[m] = *(const short8*)(wp_ + (size_t)m * 16 * IC_);                \
}

#define PREF_BF(dst) {                                                        \
    int base_ = prow + (pkx + l15) * 64 +                                     \
                ((l4 ^ (((pkx + l15) & 7) >> 1)) << 4);                       \
    _Pragma("unroll")                                                         \
    for (int n = 0; n < 8; ++n)                                               \
        dst[n] = *(const short8*)(xsb + base_ + n * 1024);                    \
    if (++pkx == 5) { pkx = 0; prow += XROWB; }                               \
}

#define COMP(afx, bfx) {                                                      \
    _Pragma("unroll")                                                         \
    for (int m = 0; m < 4; ++m)                                               \
        _Pragma("unroll")                                                     \
        for (int n = 0; n < 8; ++n)                                           \
            acc[m][n] = __builtin_amdgcn_mfma_f32_16x16x32_bf16(              \
                afx[m], bfx[n], acc[m][n], 0, 0, 0);                          \
}

__global__ __launch_bounds__(256, 2) void conv_mfma_kernel(
    const unsigned short* __restrict__ xt,
    const unsigned short* __restrict__ wt,
    float* __restrict__ out) {
    // 8 rows x 132 w x 32 ic bf16 = 67584 B (chunk-swizzled via source)
    __shared__ __align__(16) unsigned short xs[8 * XTH * IC_];

    int tid  = threadIdx.x;
    int lane = tid & 63;
    int wv   = tid >> 6;          // 0..3 = wave's h row within slab
    int l15  = lane & 15;
    int l4   = lane >> 4;         // k-chunk (ic8 group)

    int hp = blockIdx.x;          // 0..31 -> rows 4*hp..4*hp+3
    int b  = blockIdx.y;
    int cg = blockIdx.z;          // 0..7, slowest
    int cobase = cg * 64;
    int h0 = hp * 4;

    // ---- stage x slab rows h0..h0+7 (linear dest, swizzled source) ----
    {
        const unsigned short* xb = xt + (((size_t)b * XTH + h0) * XTH) * IC_;
        #pragma unroll
        for (int i = 0; i < 17; ++i) {
            int sl = i * 256 + tid;     // 16B slots, 4224 total
            if (sl < 4224) {
                int row = sl / 528;
                int rem = sl - row * 528;
                int w   = rem >> 2;
                int p   = rem & 3;
                int c   = p ^ ((w >> 1) & 3);
                gload16(&xs[sl * 8], xb + row * (XTH * IC_) + w * 32 + c * 8);
            }
        }
    }

    // per-lane A base: co = cobase + m*16 + l15, ic-chunk l4
    const unsigned short* wl = wt + (size_t)(cobase + l15) * IC_ + l4 * 8;
    const char* xsb = (const char*)xs;

    short8 afA[4], afB[4];
    PREF_AF(afA, 0);              // overlaps x staging

    f32x4 acc[4][8];
    #pragma unroll
    for (int m = 0; m < 4; ++m)
        #pragma unroll
        for (int n = 0; n < 8; ++n) acc[m][n] = (f32x4)(0.0f);

    __syncthreads();              // xs ready (drains vmcnt)

    int pkx  = 0;
    int prow = wv * XROWB;

    short8 bfA[8], bfB[8];
    PREF_BF(bfA);                 // tap 0

    #pragma unroll 1
    for (int pi = 0; pi < 12; ++pi) {
        int t0 = pi * 2;
        PREF_AF(afB, t0 + 1);
        PREF_BF(bfB);
        COMP(afA, bfA);           // tap t0
        PREF_AF(afA, t0 + 2);
        PREF_BF(bfA);
        COMP(afB, bfB);           // tap t0+1
    }
    COMP(afA, bfA);               // tap 24

    // ---- epilogue: leaky relu + store ----
    int h = h0 + wv;
    float* ob = out + ((size_t)b * COTOT_ + cobase) * HW2 + (size_t)h * HW_;
    #pragma unroll
    for (int m = 0; m < 4; ++m) {
        #pragma unroll
        for (int n = 0; n < 8; ++n) {
            #pragma unroll
            for (int r = 0; r < 4; ++r) {
                int co = m * 16 + l4 * 4 + r;
                int w  = n * 16 + l15;
                float v = acc[m][n][r];
                v = fmaxf(v, 0.01f * v);
                ob[(size_t)co * HW2 + w] = v;
            }
        }
    }
}

extern "C" void kernel_launch(void* const* d_in, const int* in_sizes, int n_in,
                              void* d_out, int out_size, void* d_ws, size_t ws_size,
                              hipStream_t stream) {
    const float* x       = (const float*)d_in[0];
    const float* kernel  = (const float*)d_in[1];
    const float* relaxed = (const float*)d_in[2];
    float* out = (float*)d_out;

    unsigned short* xt = (unsigned short*)d_ws;   // 16*132*132*32*2 = 17,842,176 B
    unsigned short* wt = (unsigned short*)((char*)d_ws + (size_t)B_ * XTH * XTH * IC_ * 2);

    const int prep_blocks = XFORM_BLOCKS + (25 * COTOT_ * IC_) / 256;  // 1089+1600
    prep_kernel<<<prep_blocks, 256, 0, stream>>>(x, kernel, relaxed, xt, wt);

    dim3 grid(HW_ / 4, B_, COTOT_ / 64);
    conv_mfma_kernel<<<grid, 256, 0, stream>>>(xt, wt, out);
}

// Round 17
// 241.239 us; speedup vs baseline: 1.1674x; 1.0306x over previous
//
#include <hip/hip_runtime.h>
#include <hip/hip_bf16.h>
#include <math.h>

// Problem constants
#define B_   16
#define IC_  32
#define HW_  128
#define NF_  8
#define OC_  64
#define K_   5
#define GRP_ 8
#define COTOT_ (OC_ * GRP_)   // 512
#define XTH  132              // padded spatial (128 + 2*2)
#define TAPSTRIDE (COTOT_ * IC_)   // elements per tap in wt
#define XROWB (XTH * IC_ * 2)      // 8448 bytes per xs row
#define HW2  (HW_ * HW_)

typedef short  short8  __attribute__((ext_vector_type(8)));
typedef unsigned short ushort8 __attribute__((ext_vector_type(8)));
typedef float  f32x4   __attribute__((ext_vector_type(4)));

static __device__ inline unsigned short f2bf(float f) {
    unsigned u = __builtin_bit_cast(unsigned, f);
    unsigned r = (u + 0x7FFFu + ((u >> 16) & 1u)) >> 16;
    return (unsigned short)r;
}

// async global -> LDS, 16 bytes per lane (dest = uniform base + lane*16)
__device__ __forceinline__ void gload16(void* lds, const void* g) {
    __builtin_amdgcn_global_load_lds(
        (const __attribute__((address_space(1))) unsigned int*)g,
        (__attribute__((address_space(3))) unsigned int*)lds, 16, 0, 0);
}

// ---------------------------------------------------------------------------
// Kernel 1: x NCHW fp32 -> padded NHWC bf16   xt[b][hp][wp][ic]
// ---------------------------------------------------------------------------
__global__ __launch_bounds__(256) void xform_kernel(
    const float* __restrict__ x, unsigned short* __restrict__ xt) {
    int idx = blockIdx.x * blockDim.x + threadIdx.x;
    const int TOT = B_ * XTH * XTH;
    if (idx >= TOT) return;
    int wp = idx % XTH;
    int t  = idx / XTH;
    int hp = t % XTH;
    int b  = t / XTH;

    unsigned short vals[IC_];
    bool interior = (hp >= 2) && (hp < 2 + HW_) && (wp >= 2) && (wp < 2 + HW_);
    if (interior) {
        const float* xb = x + ((size_t)b * IC_) * HW2 + (hp - 2) * HW_ + (wp - 2);
        #pragma unroll
        for (int ic = 0; ic < IC_; ++ic)
            vals[ic] = f2bf(xb[(size_t)ic * HW2]);
    } else {
        #pragma unroll
        for (int ic = 0; ic < IC_; ++ic) vals[ic] = 0;
    }
    ushort8* dst = (ushort8*)(xt + (size_t)idx * IC_);
    #pragma unroll
    for (int c = 0; c < 4; ++c) {
        ushort8 v;
        #pragma unroll
        for (int j = 0; j < 8; ++j) v[j] = vals[c * 8 + j];
        dst[c] = v;
    }
}

// ---------------------------------------------------------------------------
// Kernel 2: rotated+mixed weights -> bf16, layout wt[tap25][co512][ic32]
// ---------------------------------------------------------------------------
__global__ __launch_bounds__(256) void build_w_kernel(
    const float* __restrict__ kern,
    const float* __restrict__ relaxed,
    unsigned short* __restrict__ wt) {
    int idx = blockIdx.x * blockDim.x + threadIdx.x;
    const int TOT = 25 * COTOT_ * IC_;
    if (idx >= TOT) return;
    int ic = idx & (IC_ - 1);
    int t  = idx >> 5;
    int co = t & (COTOT_ - 1);
    int e  = t >> 9;            // ky*5+kx
    int a  = co & (GRP_ - 1);
    int o  = co >> 3;
    int i  = e / K_;            // ky
    int j  = e - i * K_;        // kx

    float theta = -6.283185307179586f / (float)GRP_ * (float)a;
    float cth = cosf(theta), sth = sinf(theta);
    float bx = (2.0f * (float)j + 1.0f) / (float)K_ - 1.0f;
    float by = (2.0f * (float)i + 1.0f) / (float)K_ - 1.0f;
    float gx = cth * bx - sth * by;
    float gy = sth * bx + cth * by;
    float ix = ((gx + 1.0f) * (float)K_ - 1.0f) * 0.5f;
    float iy = ((gy + 1.0f) * (float)K_ - 1.0f) * 0.5f;
    float x0 = floorf(ix), y0 = floorf(iy);
    float wx1 = ix - x0, wy1 = iy - y0;
    float wx0 = 1.0f - wx1, wy0 = 1.0f - wy1;

    float xs2[2]  = {x0, x0 + 1.0f};
    float ys2[2]  = {y0, y0 + 1.0f};
    float wxs[2] = {wx0, wx1};
    float wys[2] = {wy0, wy1};

    float tw[4];
    int   tyc[4], txc[4];
    #pragma unroll
    for (int dy = 0; dy < 2; ++dy) {
        #pragma unroll
        for (int dx = 0; dx < 2; ++dx) {
            float xx = xs2[dx], yy = ys2[dy];
            bool valid = (xx >= 0.0f) && (xx < (float)K_) &&
                         (yy >= 0.0f) && (yy < (float)K_);
            int tp = dy * 2 + dx;
            tw[tp]  = wys[dy] * wxs[dx] * (valid ? 1.0f : 0.0f);
            txc[tp] = (int)fminf(fmaxf(xx, 0.0f), (float)(K_ - 1));
            tyc[tp] = (int)fminf(fmaxf(yy, 0.0f), (float)(K_ - 1));
        }
    }

    float acc = 0.0f;
    #pragma unroll
    for (int n = 0; n < NF_; ++n) {
        const float* kb = kern + ((size_t)((n * OC_ + o) * IC_ + ic)) * (K_ * K_);
        float v = 0.0f;
        #pragma unroll
        for (int tp = 0; tp < 4; ++tp)
            v += kb[tyc[tp] * K_ + txc[tp]] * tw[tp];
        acc += relaxed[n * GRP_ + a] * v;
    }
    wt[idx] = f2bf(acc);
}

// ---------------------------------------------------------------------------
// Kernel 3: MFMA implicit-GEMM conv + leaky relu  (R13 — measured best)
// wave  = 64 co x 128 w x 1 h (4x8 frags 16x16), acc 128 + dbufs ~= 239 VGPR
// block = 4 waves = 64 co x 4 h x 128 w; LDS 67.5 KB
// -> 2 blocks/CU, 2 waves/SIMD, PHASE-DRIFTED free-running tap loop:
//    sibling block's waves cover store drain + stage latency (in-order vmcnt
//    makes them unhideable within one wave).
// A: global->VGPR reg-dbuf. w_tile=128 keeps A-L1 traffic at 26 B/cyc/CU.
// B: swizzled LDS slab (conflict-free), reg-dbuf reads. Barrier-free loop.
// ---------------------------------------------------------------------------
#define PREF_AF(dst, tap) {                                                   \
    const unsigned short* wp_ = wl + (size_t)(tap) * TAPSTRIDE;               \
    _Pragma("unroll")                                                         \
    for (int m = 0; m < 4; ++m)                                               \
        dst[m] = *(const short8*)(wp_ + (size_t)m * 16 * IC_);                \
}

#define PREF_BF(dst) {                                                        \
    int base_ = prow + (pkx + l15) * 64 +                                     \
                ((l4 ^ (((pkx + l15) & 7) >> 1)) << 4);                       \
    _Pragma("unroll")                                                         \
    for (int n = 0; n < 8; ++n)                                               \
        dst[n] = *(const short8*)(xsb + base_ + n * 1024);                    \
    if (++pkx == 5) { pkx = 0; prow += XROWB; }                               \
}

#define COMP(afx, bfx) {                                                      \
    __builtin_amdgcn_s_setprio(1);                                            \
    _Pragma("unroll")                                                         \
    for (int m = 0; m < 4; ++m)                                               \
        _Pragma("unroll")                                                     \
        for (int n = 0; n < 8; ++n)                                           \
            acc[m][n] = __builtin_amdgcn_mfma_f32_16x16x32_bf16(              \
                afx[m], bfx[n], acc[m][n], 0, 0, 0);                          \
    __builtin_amdgcn_s_setprio(0);                                            \
}

__global__ __launch_bounds__(256, 2) void conv_mfma_kernel(
    const unsigned short* __restrict__ xt,
    const unsigned short* __restrict__ wt,
    float* __restrict__ out) {
    // 8 rows x 132 w x 32 ic bf16 = 67584 B (chunk-swizzled via source)
    __shared__ __align__(16) unsigned short xs[8 * XTH * IC_];

    int tid  = threadIdx.x;
    int lane = tid & 63;
    int wv   = tid >> 6;          // 0..3 = wave's h row within slab
    int l15  = lane & 15;
    int l4   = lane >> 4;         // k-chunk (ic8 group)

    int hp = blockIdx.x;          // 0..31 -> rows 4*hp..4*hp+3
    int b  = blockIdx.y;
    int cg = blockIdx.z;          // 0..7, slowest
    int cobase = cg * 64;
    int h0 = hp * 4;

    // ---- stage x slab rows h0..h0+7 (linear dest, swizzled source) ----
    {
        const unsigned short* xb = xt + (((size_t)b * XTH + h0) * XTH) * IC_;
        #pragma unroll
        for (int i = 0; i < 17; ++i) {
            int sl = i * 256 + tid;     // 16B slots, 4224 total
            if (sl < 4224) {
                int row = sl / 528;
                int rem = sl - row * 528;
                int w   = rem >> 2;
                int p   = rem & 3;
                int c   = p ^ ((w >> 1) & 3);
                gload16(&xs[sl * 8], xb + row * (XTH * IC_) + w * 32 + c * 8);
            }
        }
    }

    // per-lane A base: co = cobase + m*16 + l15, ic-chunk l4
    const unsigned short* wl = wt + (size_t)(cobase + l15) * IC_ + l4 * 8;
    const char* xsb = (const char*)xs;

    short8 afA[4], afB[4];
    PREF_AF(afA, 0);              // overlaps x staging

    f32x4 acc[4][8];
    #pragma unroll
    for (int m = 0; m < 4; ++m)
        #pragma unroll
        for (int n = 0; n < 8; ++n) acc[m][n] = (f32x4)(0.0f);

    __syncthreads();              // xs ready (drains vmcnt)

    int pkx  = 0;
    int prow = wv * XROWB;

    short8 bfA[8], bfB[8];
    PREF_BF(bfA);                 // tap 0

    #pragma unroll 1
    for (int pi = 0; pi < 12; ++pi) {
        int t0 = pi * 2;
        PREF_AF(afB, t0 + 1);
        PREF_BF(bfB);
        COMP(afA, bfA);           // tap t0
        PREF_AF(afA, t0 + 2);
        PREF_BF(bfA);
        COMP(afB, bfB);           // tap t0+1
    }
    COMP(afA, bfA);               // tap 24

    // ---- epilogue: leaky relu + store ----
    int h = h0 + wv;
    float* ob = out + ((size_t)b * COTOT_ + cobase) * HW2 + (size_t)h * HW_;
    #pragma unroll
    for (int m = 0; m < 4; ++m) {
        #pragma unroll
        for (int n = 0; n < 8; ++n) {
            #pragma unroll
            for (int r = 0; r < 4; ++r) {
                int co = m * 16 + l4 * 4 + r;
                int w  = n * 16 + l15;
                float v = acc[m][n][r];
                v = fmaxf(v, 0.01f * v);
                ob[(size_t)co * HW2 + w] = v;
            }
        }
    }
}

extern "C" void kernel_launch(void* const* d_in, const int* in_sizes, int n_in,
                              void* d_out, int out_size, void* d_ws, size_t ws_size,
                              hipStream_t stream) {
    const float* x       = (const float*)d_in[0];
    const float* kernel  = (const float*)d_in[1];
    const float* relaxed = (const float*)d_in[2];
    float* out = (float*)d_out;

    unsigned short* xt = (unsigned short*)d_ws;   // 16*132*132*32*2 = 17,842,176 B
    unsigned short* wt = (unsigned short*)((char*)d_ws + (size_t)B_ * XTH * XTH * IC_ * 2);

    const int xtot = B_ * XTH * XTH;
    xform_kernel<<<(xtot + 255) / 256, 256, 0, stream>>>(x, xt);

    const int wtot = 25 * COTOT_ * IC_;
    build_w_kernel<<<(wtot + 255) / 256, 256, 0, stream>>>(kernel, relaxed, wt);

    dim3 grid(HW_ / 4, B_, COTOT_ / 64);
    conv_mfma_kernel<<<grid, 256, 0, stream>>>(xt, wt, out);
}

// Round 18
// 222.060 us; speedup vs baseline: 1.2682x; 1.0864x over previous
//
#include <hip/hip_runtime.h>
#include <hip/hip_bf16.h>
#include <math.h>

// Problem constants
#define B_   16
#define IC_  32
#define HW_  128
#define NF_  8
#define OC_  64
#define K_   5
#define GRP_ 8
#define COTOT_ (OC_ * GRP_)   // 512
#define XTH  132              // padded spatial (128 + 2*2)
#define TAPSTRIDE (COTOT_ * IC_)   // elements per tap in wt
#define XROWB (XTH * IC_ * 2)      // 8448 bytes per xs row
#define HW2  (HW_ * HW_)

typedef short  short8  __attribute__((ext_vector_type(8)));
typedef unsigned short ushort8 __attribute__((ext_vector_type(8)));
typedef float  f32x4   __attribute__((ext_vector_type(4)));

static __device__ inline unsigned short f2bf(float f) {
    unsigned u = __builtin_bit_cast(unsigned, f);
    unsigned r = (u + 0x7FFFu + ((u >> 16) & 1u)) >> 16;
    return (unsigned short)r;
}

// async global -> LDS, 16 bytes per lane (dest = uniform base + lane*16)
__device__ __forceinline__ void gload16(void* lds, const void* g) {
    __builtin_amdgcn_global_load_lds(
        (const __attribute__((address_space(1))) unsigned int*)g,
        (__attribute__((address_space(3))) unsigned int*)lds, 16, 0, 0);
}

// ---------------------------------------------------------------------------
// Kernel 1: x NCHW fp32 -> padded NHWC bf16   xt[b][hp][wp][ic]
// ---------------------------------------------------------------------------
__global__ __launch_bounds__(256) void xform_kernel(
    const float* __restrict__ x, unsigned short* __restrict__ xt) {
    int idx = blockIdx.x * blockDim.x + threadIdx.x;
    const int TOT = B_ * XTH * XTH;
    if (idx >= TOT) return;
    int wp = idx % XTH;
    int t  = idx / XTH;
    int hp = t % XTH;
    int b  = t / XTH;

    unsigned short vals[IC_];
    bool interior = (hp >= 2) && (hp < 2 + HW_) && (wp >= 2) && (wp < 2 + HW_);
    if (interior) {
        const float* xb = x + ((size_t)b * IC_) * HW2 + (hp - 2) * HW_ + (wp - 2);
        #pragma unroll
        for (int ic = 0; ic < IC_; ++ic)
            vals[ic] = f2bf(xb[(size_t)ic * HW2]);
    } else {
        #pragma unroll
        for (int ic = 0; ic < IC_; ++ic) vals[ic] = 0;
    }
    ushort8* dst = (ushort8*)(xt + (size_t)idx * IC_);
    #pragma unroll
    for (int c = 0; c < 4; ++c) {
        ushort8 v;
        #pragma unroll
        for (int j = 0; j < 8; ++j) v[j] = vals[c * 8 + j];
        dst[c] = v;
    }
}

// ---------------------------------------------------------------------------
// Kernel 2: rotated+mixed weights -> bf16, layout wt[tap25][co512][ic32]
// ---------------------------------------------------------------------------
__global__ __launch_bounds__(256) void build_w_kernel(
    const float* __restrict__ kern,
    const float* __restrict__ relaxed,
    unsigned short* __restrict__ wt) {
    int idx = blockIdx.x * blockDim.x + threadIdx.x;
    const int TOT = 25 * COTOT_ * IC_;
    if (idx >= TOT) return;
    int ic = idx & (IC_ - 1);
    int t  = idx >> 5;
    int co = t & (COTOT_ - 1);
    int e  = t >> 9;            // ky*5+kx
    int a  = co & (GRP_ - 1);
    int o  = co >> 3;
    int i  = e / K_;            // ky
    int j  = e - i * K_;        // kx

    float theta = -6.283185307179586f / (float)GRP_ * (float)a;
    float cth = cosf(theta), sth = sinf(theta);
    float bx = (2.0f * (float)j + 1.0f) / (float)K_ - 1.0f;
    float by = (2.0f * (float)i + 1.0f) / (float)K_ - 1.0f;
    float gx = cth * bx - sth * by;
    float gy = sth * bx + cth * by;
    float ix = ((gx + 1.0f) * (float)K_ - 1.0f) * 0.5f;
    float iy = ((gy + 1.0f) * (float)K_ - 1.0f) * 0.5f;
    float x0 = floorf(ix), y0 = floorf(iy);
    float wx1 = ix - x0, wy1 = iy - y0;
    float wx0 = 1.0f - wx1, wy0 = 1.0f - wy1;

    float xs2[2]  = {x0, x0 + 1.0f};
    float ys2[2]  = {y0, y0 + 1.0f};
    float wxs[2] = {wx0, wx1};
    float wys[2] = {wy0, wy1};

    float tw[4];
    int   tyc[4], txc[4];
    #pragma unroll
    for (int dy = 0; dy < 2; ++dy) {
        #pragma unroll
        for (int dx = 0; dx < 2; ++dx) {
            float xx = xs2[dx], yy = ys2[dy];
            bool valid = (xx >= 0.0f) && (xx < (float)K_) &&
                         (yy >= 0.0f) && (yy < (float)K_);
            int tp = dy * 2 + dx;
            tw[tp]  = wys[dy] * wxs[dx] * (valid ? 1.0f : 0.0f);
            txc[tp] = (int)fminf(fmaxf(xx, 0.0f), (float)(K_ - 1));
            tyc[tp] = (int)fminf(fmaxf(yy, 0.0f), (float)(K_ - 1));
        }
    }

    float acc = 0.0f;
    #pragma unroll
    for (int n = 0; n < NF_; ++n) {
        const float* kb = kern + ((size_t)((n * OC_ + o) * IC_ + ic)) * (K_ * K_);
        float v = 0.0f;
        #pragma unroll
        for (int tp = 0; tp < 4; ++tp)
            v += kb[tyc[tp] * K_ + txc[tp]] * tw[tp];
        acc += relaxed[n * GRP_ + a] * v;
    }
    wt[idx] = f2bf(acc);
}

// ---------------------------------------------------------------------------
// Kernel 3: MFMA implicit-GEMM conv + leaky relu  (R13 + XCD-aware swizzle)
// wave  = 64 co x 128 w x 1 h (4x8 frags 16x16), acc 128 + dbufs ~= 239 VGPR
// block = 4 waves = 64 co x 4 h x 128 w; LDS 67.5 KB
// -> 2 blocks/CU, 2 waves/SIMD, PHASE-DRIFTED free-running tap loop.
// T1 grid swizzle (nwg=4096 % 8 == 0, bijective): XCD k gets exactly cg=k
// -> wt slice (200 KB) L2-resident per XCD; contiguous hp runs share halo
//    rows in L2 instead of re-fetching via L3.
// A: global->VGPR reg-dbuf. B: swizzled LDS slab, reg-dbuf reads.
// ---------------------------------------------------------------------------
#define PREF_AF(dst, tap) {                                                   \
    const unsigned short* wp_ = wl + (size_t)(tap) * TAPSTRIDE;               \
    _Pragma("unroll")                                                         \
    for (int m = 0; m < 4; ++m)                                               \
        dst[m] = *(const short8*)(wp_ + (size_t)m * 16 * IC_);                \
}

#define PREF_BF(dst) {                                                        \
    int base_ = prow + (pkx + l15) * 64 +                                     \
                ((l4 ^ (((pkx + l15) & 7) >> 1)) << 4);                       \
    _Pragma("unroll")                                                         \
    for (int n = 0; n < 8; ++n)                                               \
        dst[n] = *(const short8*)(xsb + base_ + n * 1024);                    \
    if (++pkx == 5) { pkx = 0; prow += XROWB; }                               \
}

#define COMP(afx, bfx) {                                                      \
    __builtin_amdgcn_s_setprio(1);                                            \
    _Pragma("unroll")                                                         \
    for (int m = 0; m < 4; ++m)                                               \
        _Pragma("unroll")                                                     \
        for (int n = 0; n < 8; ++n)                                           \
            acc[m][n] = __builtin_amdgcn_mfma_f32_16x16x32_bf16(              \
                afx[m], bfx[n], acc[m][n], 0, 0, 0);                          \
    __builtin_amdgcn_s_setprio(0);                                            \
}

__global__ __launch_bounds__(256, 2) void conv_mfma_kernel(
    const unsigned short* __restrict__ xt,
    const unsigned short* __restrict__ wt,
    float* __restrict__ out) {
    // 8 rows x 132 w x 32 ic bf16 = 67584 B (chunk-swizzled via source)
    __shared__ __align__(16) unsigned short xs[8 * XTH * IC_];

    int tid  = threadIdx.x;
    int lane = tid & 63;
    int wv   = tid >> 6;          // 0..3 = wave's h row within slab
    int l15  = lane & 15;
    int l4   = lane >> 4;         // k-chunk (ic8 group)

    // ---- T1: bijective XCD-aware remap (nwg = 4096 = 8 * 512) ----
    // dispatch round-robins raw%8 across XCDs; this gives XCD k the
    // contiguous bid range [512k, 512k+512) = exactly cg k, hp-contiguous.
    int raw = blockIdx.x;
    int bid = (raw & 7) * 512 + (raw >> 3);
    int hp  = bid & 31;           // fastest: halo-sharing neighbors adjacent
    int b   = (bid >> 5) & 15;
    int cg  = bid >> 9;           // one cg per XCD
    int cobase = cg * 64;
    int h0 = hp * 4;

    // ---- stage x slab rows h0..h0+7 (linear dest, swizzled source) ----
    {
        const unsigned short* xb = xt + (((size_t)b * XTH + h0) * XTH) * IC_;
        #pragma unroll
        for (int i = 0; i < 17; ++i) {
            int sl = i * 256 + tid;     // 16B slots, 4224 total
            if (sl < 4224) {
                int row = sl / 528;
                int rem = sl - row * 528;
                int w   = rem >> 2;
                int p   = rem & 3;
                int c   = p ^ ((w >> 1) & 3);
                gload16(&xs[sl * 8], xb + row * (XTH * IC_) + w * 32 + c * 8);
            }
        }
    }

    // per-lane A base: co = cobase + m*16 + l15, ic-chunk l4
    const unsigned short* wl = wt + (size_t)(cobase + l15) * IC_ + l4 * 8;
    const char* xsb = (const char*)xs;

    short8 afA[4], afB[4];
    PREF_AF(afA, 0);              // overlaps x staging

    f32x4 acc[4][8];
    #pragma unroll
    for (int m = 0; m < 4; ++m)
        #pragma unroll
        for (int n = 0; n < 8; ++n) acc[m][n] = (f32x4)(0.0f);

    __syncthreads();              // xs ready (drains vmcnt)

    int pkx  = 0;
    int prow = wv * XROWB;

    short8 bfA[8], bfB[8];
    PREF_BF(bfA);                 // tap 0

    #pragma unroll 1
    for (int pi = 0; pi < 12; ++pi) {
        int t0 = pi * 2;
        PREF_AF(afB, t0 + 1);
        PREF_BF(bfB);
        COMP(afA, bfA);           // tap t0
        PREF_AF(afA, t0 + 2);
        PREF_BF(bfA);
        COMP(afB, bfB);           // tap t0+1
    }
    COMP(afA, bfA);               // tap 24

    // ---- epilogue: leaky relu + store ----
    int h = h0 + wv;
    float* ob = out + ((size_t)b * COTOT_ + cobase) * HW2 + (size_t)h * HW_;
    #pragma unroll
    for (int m = 0; m < 4; ++m) {
        #pragma unroll
        for (int n = 0; n < 8; ++n) {
            #pragma unroll
            for (int r = 0; r < 4; ++r) {
                int co = m * 16 + l4 * 4 + r;
                int w  = n * 16 + l15;
                float v = acc[m][n][r];
                v = fmaxf(v, 0.01f * v);
                ob[(size_t)co * HW2 + w] = v;
            }
        }
    }
}

extern "C" void kernel_launch(void* const* d_in, const int* in_sizes, int n_in,
                              void* d_out, int out_size, void* d_ws, size_t ws_size,
                              hipStream_t stream) {
    const float* x       = (const float*)d_in[0];
    const float* kernel  = (const float*)d_in[1];
    const float* relaxed = (const float*)d_in[2];
    float* out = (float*)d_out;

    unsigned short* xt = (unsigned short*)d_ws;   // 16*132*132*32*2 = 17,842,176 B
    unsigned short* wt = (unsigned short*)((char*)d_ws + (size_t)B_ * XTH * XTH * IC_ * 2);

    const int xtot = B_ * XTH * XTH;
    xform_kernel<<<(xtot + 255) / 256, 256, 0, stream>>>(x, xt);

    const int wtot = 25 * COTOT_ * IC_;
    build_w_kernel<<<(wtot + 255) / 256, 256, 0, stream>>>(kernel, relaxed, wt);

    conv_mfma_kernel<<<4096, 256, 0, stream>>>(xt, wt, out);
}